// Round 12
// baseline (297.017 us; speedup 1.0000x reference)
//
#include <hip/hip_runtime.h>
#include <hip/hip_bf16.h>

// C2QAttention: softmax(sim[B,C,Q], axis=Q) @ enc[B,Q,D] -> out[B,C,D]
// B=32, C=4096, Q=512, D=512. fp32 in/out; bf16 MFMA, deferred normalization:
// out = (exp(sim) @ enc) * (1/rowsum).
//
// Round 12: inverted blocking, barrier-free streaming.
// Block = (b, 64-D-col group dg, C-half rh). Stage the 64 KB Et slice
// (fragment-major -> linear copy) into LDS ONCE (single __syncthreads in the
// whole kernel), then 8 waves free-run over 2048 C-rows in 8 chunks of 256:
//   wave = 32 rows x 64 cols, K=512; A-frags loaded DIRECT from sim
//   (R5's ideal-coalescing map), 2-slot ks-pipeline, exp+pack in registers,
//   B-frags via ds_read_b128 from the LDS panel, rowsum lane-local + shfl.
// b pinned to XCD (= b%8) so the 8 dg-siblings share sim rows via XCD L2.

constexpr int Bn = 32;
constexpr int Cn = 4096;
constexpr int Qn = 512;
constexpr int Dn = 512;

typedef __attribute__((ext_vector_type(8))) short short8;
typedef __attribute__((ext_vector_type(4))) float floatx4;

__device__ __forceinline__ ushort f2bf(float f) {
  union { float f; unsigned u; } v; v.f = f;
  unsigned r = v.u + 0x7FFFu + ((v.u >> 16) & 1u);   // RNE
  return (ushort)(r >> 16);
}

__device__ __forceinline__ short8 exp_pack8(float4 x, float4 y, float& rsum) {
  float e0 = __expf(x.x), e1 = __expf(x.y), e2 = __expf(x.z), e3 = __expf(x.w);
  float e4 = __expf(y.x), e5 = __expf(y.y), e6 = __expf(y.z), e7 = __expf(y.w);
  rsum += ((e0 + e1) + (e2 + e3)) + ((e4 + e5) + (e6 + e7));
  union { uint4 u; short8 s8; } pk;
  pk.u.x = (uint)f2bf(e0) | ((uint)f2bf(e1) << 16);
  pk.u.y = (uint)f2bf(e2) | ((uint)f2bf(e3) << 16);
  pk.u.z = (uint)f2bf(e4) | ((uint)f2bf(e5) << 16);
  pk.u.w = (uint)f2bf(e6) | ((uint)f2bf(e7) << 16);
  return pk.s8;
}

// enc[b][q][d] f32 -> Etf fragment-major: [b][dtile(32)][kidx(16)][lane(64)]x16B
// chunk(b,dt,kidx): lane=lhi*16+l16 holds bf16[j]=enc[b][kidx*32+lhi*8+j][dt*16+l16]
__global__ __launch_bounds__(256) void enc_to_frag(const float* __restrict__ E,
                                                   ushort* __restrict__ Etf) {
  const int ks = blockIdx.x, b = blockIdx.y;
  const int t = threadIdx.x;
  const int lane = t & 63, grp = t >> 6;
  const int l16 = lane & 15, lhi = lane >> 4;
  const float* src = E + ((size_t)b * Qn + ks * 32 + lhi * 8) * Dn + l16;
#pragma unroll
  for (int dt8 = 0; dt8 < 8; ++dt8) {
    int dt = grp * 8 + dt8;
    float e[8];
#pragma unroll
    for (int j = 0; j < 8; ++j) e[j] = src[(size_t)j * Dn + dt * 16];
    uint4 pk;
    pk.x = (uint)f2bf(e[0]) | ((uint)f2bf(e[1]) << 16);
    pk.y = (uint)f2bf(e[2]) | ((uint)f2bf(e[3]) << 16);
    pk.z = (uint)f2bf(e[4]) | ((uint)f2bf(e[5]) << 16);
    pk.w = (uint)f2bf(e[6]) | ((uint)f2bf(e[7]) << 16);
    *(uint4*)((char*)Etf + (((size_t)(b * 32 + dt) * 16 + ks) * 64 + lane) * 16) = pk;
  }
}

__global__ __launch_bounds__(512, 4) void c2q_fused(const float* __restrict__ sim,
                                                    const ushort* __restrict__ Etf,
                                                    float* __restrict__ out) {
  __shared__ char Bp[65536];  // Et slice: [dt4][kidx16][lane64] x 16B

  const int tid  = threadIdx.x;
  const int lane = tid & 63;
  const int w    = tid >> 6;           // 0..7 -> 32-row group within chunk
  const int l16  = lane & 15;
  const int lhi  = lane >> 4;          // 0..3

  // grid 512 = blo(8) x bhi(4) x rh(2) x dg(8); XCD = lin&7 = b%8
  const int lin = blockIdx.x;
  const int blo = lin & 7;
  const int bhi = (lin >> 3) & 3;
  const int rh  = (lin >> 5) & 1;
  const int dg  = lin >> 6;            // 0..7 -> 64 D-cols
  const int b   = bhi * 8 + blo;

  // ---- stage the Et panel (64 KB) into LDS once ----
  const uint4* esrc = (const uint4*)((const char*)Etf +
                      (size_t)(b * 32 + dg * 4) * 16 * 64 * 16);
#pragma unroll
  for (int it = 0; it < 8; ++it) {
    uint4 tmp = esrc[it * 512 + tid];
    *(uint4*)(Bp + ((size_t)it * 512 + tid) * 16) = tmp;
  }
  __syncthreads();                     // the only barrier in the kernel

  // A-frag load base: row = rh*2048 + ch*256 + w*32 + mr*16 + l16, k = lhi*8
  const float* s0 = sim + ((size_t)b * Cn + rh * 2048 + w * 32 + l16) * Qn + lhi * 8;
  float* outp = out + ((size_t)b * Cn + rh * 2048 + w * 32) * Dn + dg * 64;

#pragma unroll 1
  for (int ch = 0; ch < 8; ++ch) {
    const float* sc = s0 + (size_t)ch * 256 * Qn;

    float4 vs[2][4];   // [slot][mr*2+half], 2-slot ks-pipeline
#pragma unroll
    for (int sl = 0; sl < 2; ++sl) {
      vs[sl][0] = *(const float4*)(sc + sl * 32);
      vs[sl][1] = *(const float4*)(sc + sl * 32 + 4);
      vs[sl][2] = *(const float4*)(sc + (size_t)16 * Qn + sl * 32);
      vs[sl][3] = *(const float4*)(sc + (size_t)16 * Qn + sl * 32 + 4);
    }

    floatx4 acc[2][4] = {};
    float r0 = 0.0f, r1 = 0.0f;

#pragma unroll
    for (int ks = 0; ks < 16; ++ks) {
      const int sl = ks & 1;
      // exp + pack A-frags from the batch loaded 2 iterations ago
      short8 a0 = exp_pack8(vs[sl][0], vs[sl][1], r0);
      short8 a1 = exp_pack8(vs[sl][2], vs[sl][3], r1);
      // refill the slot with ks+2
      if (ks < 14) {
        vs[sl][0] = *(const float4*)(sc + (ks + 2) * 32);
        vs[sl][1] = *(const float4*)(sc + (ks + 2) * 32 + 4);
        vs[sl][2] = *(const float4*)(sc + (size_t)16 * Qn + (ks + 2) * 32);
        vs[sl][3] = *(const float4*)(sc + (size_t)16 * Qn + (ks + 2) * 32 + 4);
      }
      // B-frags from LDS panel (2-way bank aliasing = free)
      short8 bb[4];
#pragma unroll
      for (int nr = 0; nr < 4; ++nr)
        bb[nr] = *(const short8*)(Bp + (((nr * 16 + ks) * 64 + lane) << 4));
      __builtin_amdgcn_sched_barrier(0);
      __builtin_amdgcn_s_setprio(1);
#pragma unroll
      for (int nr = 0; nr < 4; ++nr) {
        acc[0][nr] = __builtin_amdgcn_mfma_f32_16x16x32_bf16(a0, bb[nr], acc[0][nr], 0, 0, 0);
        acc[1][nr] = __builtin_amdgcn_mfma_f32_16x16x32_bf16(a1, bb[nr], acc[1][nr], 0, 0, 0);
      }
      __builtin_amdgcn_s_setprio(0);
    }

    // rowsums: lanes {l16, l16+16, l16+32, l16+48} hold partials of row l16
    r0 += __shfl_xor(r0, 16); r0 += __shfl_xor(r0, 32);
    r1 += __shfl_xor(r1, 16); r1 += __shfl_xor(r1, 32);
    float inv0 = 1.0f / r0, inv1 = 1.0f / r1;

    // store 32 rows x 64 cols, scaled by 1/rowsum
#pragma unroll
    for (int mr = 0; mr < 2; ++mr) {
      float rs[4];
#pragma unroll
      for (int rr = 0; rr < 4; ++rr)
        rs[rr] = __shfl(mr == 0 ? inv0 : inv1, lhi * 4 + rr);
#pragma unroll
      for (int nr = 0; nr < 4; ++nr) {
#pragma unroll
        for (int rr = 0; rr < 4; ++rr) {
          int row = mr * 16 + lhi * 4 + rr;
          outp[((size_t)ch * 256 + row) * Dn + nr * 16 + l16] = acc[mr][nr][rr] * rs[rr];
        }
      }
    }
  }
}

extern "C" void kernel_launch(void* const* d_in, const int* in_sizes, int n_in,
                              void* d_out, int out_size, void* d_ws, size_t ws_size,
                              hipStream_t stream) {
  const float* sim = (const float*)d_in[0];
  const float* enc = (const float*)d_in[1];
  float* outp = (float*)d_out;
  ushort* Etf = (ushort*)d_ws;  // 32*32*16*64*16 B = 16.8 MB

  enc_to_frag<<<dim3(16, Bn), 256, 0, stream>>>(enc, Etf);
  c2q_fused<<<dim3(512), 512, 0, stream>>>(sim, Etf, outp);
}

// Round 14
// 176.625 us; speedup vs baseline: 1.6816x; 1.6816x over previous
//
#include <hip/hip_runtime.h>
#include <hip/hip_bf16.h>

// C2QAttention: softmax(sim[B,C,Q], axis=Q) @ enc[B,Q,D] -> out[B,C,D]
// B=32, C=4096, Q=512, D=512. fp32 in/out; bf16 MFMA, deferred normalization.
// Round 14 = Round 13 (BK=128, 4 K-steps) with the staging address bug fixed:
// thread so covers 16 k = 32 B at byte (srow*256 + so*32 + q*16) ^ swz —
// XOR applied to the FINAL linear address (never add after XOR).

constexpr int Bn = 32;
constexpr int Cn = 4096;
constexpr int Qn = 512;
constexpr int Dn = 512;

typedef __attribute__((ext_vector_type(8))) short short8;
typedef __attribute__((ext_vector_type(4))) float floatx4;

__device__ __forceinline__ ushort f2bf(float f) {
  union { float f; unsigned u; } v; v.f = f;
  unsigned r = v.u + 0x7FFFu + ((v.u >> 16) & 1u);   // RNE
  return (ushort)(r >> 16);
}

__device__ __forceinline__ uint4 exp_pack(float4 x, float4 y, float& rsum) {
  float e0 = __expf(x.x), e1 = __expf(x.y), e2 = __expf(x.z), e3 = __expf(x.w);
  float e4 = __expf(y.x), e5 = __expf(y.y), e6 = __expf(y.z), e7 = __expf(y.w);
  rsum += ((e0 + e1) + (e2 + e3)) + ((e4 + e5) + (e6 + e7));
  uint4 pk;
  pk.x = (uint)f2bf(e0) | ((uint)f2bf(e1) << 16);
  pk.y = (uint)f2bf(e2) | ((uint)f2bf(e3) << 16);
  pk.z = (uint)f2bf(e4) | ((uint)f2bf(e5) << 16);
  pk.w = (uint)f2bf(e6) | ((uint)f2bf(e7) << 16);
  return pk;
}

// enc[b][q][d] f32 -> Etf fragment-major: [b][dtile(32)][kidx(16)][lane(64)]x16B
// chunk(b,dt,kidx): lane=lhi*16+l16 holds bf16[j]=enc[b][kidx*32+lhi*8+j][dt*16+l16]
__global__ __launch_bounds__(256) void enc_to_frag(const float* __restrict__ E,
                                                   ushort* __restrict__ Etf) {
  const int ks = blockIdx.x, b = blockIdx.y;
  const int t = threadIdx.x;
  const int lane = t & 63, grp = t >> 6;
  const int l16 = lane & 15, lhi = lane >> 4;
  const float* src = E + ((size_t)b * Qn + ks * 32 + lhi * 8) * Dn + l16;
#pragma unroll
  for (int dt8 = 0; dt8 < 8; ++dt8) {
    int dt = grp * 8 + dt8;
    float e[8];
#pragma unroll
    for (int j = 0; j < 8; ++j) e[j] = src[(size_t)j * Dn + dt * 16];
    uint4 pk;
    pk.x = (uint)f2bf(e[0]) | ((uint)f2bf(e[1]) << 16);
    pk.y = (uint)f2bf(e[2]) | ((uint)f2bf(e[3]) << 16);
    pk.z = (uint)f2bf(e[4]) | ((uint)f2bf(e[5]) << 16);
    pk.w = (uint)f2bf(e[6]) | ((uint)f2bf(e[7]) << 16);
    *(uint4*)((char*)Etf + (((size_t)(b * 32 + dt) * 16 + ks) * 64 + lane) * 16) = pk;
  }
}

__global__ __launch_bounds__(512, 2) void c2q_fused(const float* __restrict__ sim,
                                                    const ushort* __restrict__ Etf,
                                                    float* __restrict__ out) {
  __shared__ char Abuf[2][64 * 256];   // [buf][row*256B] bf16, XOR-swizzled
  __shared__ float rsInv[64];

  const int tid  = threadIdx.x;
  const int lane = tid & 63;
  const int wid  = tid >> 6;           // 0..7 -> 64 D-cols each
  const int l16  = lane & 15;
  const int lhi  = lane >> 4;          // 0..3

  // b-pinned XCD grid: XCD = lin&7 -> 4 b per XCD, Et 2MB per XCD L2
  const int lin = blockIdx.x;          // 2048 = 64 mtiles x 32 b
  const int blo = lin & 7;
  const int bhi = (lin >> 3) & 3;
  const int mt  = lin >> 5;
  const int b   = bhi * 8 + blo;
  const int c0  = mt * 64;

  // staging: thread owns (row srow, 16-float k-span so) per 128-k step
  const int srow = tid >> 3;           // 0..63
  const int so   = tid & 7;            // 0..7 -> k offset so*16 within step
  const float* sload = sim + ((size_t)b * Cn + c0 + srow) * Qn + so * 16;
  const int swz = (srow & 7) << 4;
  const int sbase = srow * 256 + so * 32;   // XOR applied at final address

  // B-frag base: chunk (b, dt = wid*4 + nr, kidx), this lane's 16B
  const short8* EB = (const short8*)Etf + ((size_t)(b * 32 + wid * 4) * 16) * 64 + lane;

  float rsum = 0.0f;
  floatx4 acc[4][4] = {};
  float4 vs[2][4];                     // 2 slots x 4 float4 (static-indexed)
  short8 bfr[2][4];                    // B-frag 2-deep rotate

  // ---- prologue: step0 -> slot0 -> Abuf[0]; step1 -> slot1; B kidx 0,1 ----
#pragma unroll
  for (int q = 0; q < 4; ++q) {
    vs[0][q] = *(const float4*)(sload + q * 4);
    vs[1][q] = *(const float4*)(sload + 128 + q * 4);
  }
#pragma unroll
  for (int nr = 0; nr < 4; ++nr) {
    bfr[0][nr] = EB[((size_t)nr * 16 + 0) * 64];
    bfr[1][nr] = EB[((size_t)nr * 16 + 1) * 64];
  }
  *(uint4*)(Abuf[0] + (sbase ^ swz))        = exp_pack(vs[0][0], vs[0][1], rsum);
  *(uint4*)(Abuf[0] + ((sbase + 16) ^ swz)) = exp_pack(vs[0][2], vs[0][3], rsum);
  __syncthreads();

#pragma unroll
  for (int t = 0; t < 4; ++t) {
    // (a) issue sim loads for step t+2 into the slot freed at step t-1
    if (t < 2) {
#pragma unroll
      for (int q = 0; q < 4; ++q)
        vs[t & 1][q] = *(const float4*)(sload + (t + 2) * 128 + q * 4);
    }
    __builtin_amdgcn_sched_barrier(0);

    // (b) MFMA on Abuf[t&1], 4 k-slices of 32
#pragma unroll
    for (int ks = 0; ks < 4; ++ks) {
      const int kidx = 4 * t + ks;
      short8 a[4];
#pragma unroll
      for (int mr = 0; mr < 4; ++mr) {
        int row = mr * 16 + l16;
        a[mr] = *(const short8*)(Abuf[t & 1] +
                 ((row * 256 + ks * 64 + lhi * 16) ^ ((row & 7) << 4)));
      }
      __builtin_amdgcn_s_setprio(1);
#pragma unroll
      for (int mr = 0; mr < 4; ++mr)
#pragma unroll
        for (int nr = 0; nr < 4; ++nr)
          acc[mr][nr] = __builtin_amdgcn_mfma_f32_16x16x32_bf16(
              a[mr], bfr[kidx & 1][nr], acc[mr][nr], 0, 0, 0);
      __builtin_amdgcn_s_setprio(0);
      // refill just-consumed B slot with kidx+2 (2-deep, L2-resident)
      if (kidx < 14) {
#pragma unroll
        for (int nr = 0; nr < 4; ++nr)
          bfr[kidx & 1][nr] = EB[((size_t)nr * 16 + kidx + 2) * 64];
      }
    }

    // (c) exp + stage step t+1 into Abuf[(t+1)&1]; last step: finalize rowsum
    if (t < 3) {
      *(uint4*)(Abuf[(t + 1) & 1] + (sbase ^ swz)) =
          exp_pack(vs[(t + 1) & 1][0], vs[(t + 1) & 1][1], rsum);
      *(uint4*)(Abuf[(t + 1) & 1] + ((sbase + 16) ^ swz)) =
          exp_pack(vs[(t + 1) & 1][2], vs[(t + 1) & 1][3], rsum);
    } else {
      rsum += __shfl_xor(rsum, 1);
      rsum += __shfl_xor(rsum, 2);
      rsum += __shfl_xor(rsum, 4);
      if (so == 0) rsInv[srow] = 1.0f / rsum;
    }
    __syncthreads();
  }

  // ---- epilogue: scale by 1/rowsum, store ----
  float* outp = out + ((size_t)b * Cn + c0) * Dn + wid * 64;
#pragma unroll
  for (int mr = 0; mr < 4; ++mr) {
    float rs[4];
#pragma unroll
    for (int rr = 0; rr < 4; ++rr) rs[rr] = rsInv[mr * 16 + lhi * 4 + rr];
#pragma unroll
    for (int nr = 0; nr < 4; ++nr) {
#pragma unroll
      for (int rr = 0; rr < 4; ++rr) {
        int row = mr * 16 + lhi * 4 + rr;
        outp[(size_t)row * Dn + nr * 16 + l16] = acc[mr][nr][rr] * rs[rr];
      }
    }
  }
}

extern "C" void kernel_launch(void* const* d_in, const int* in_sizes, int n_in,
                              void* d_out, int out_size, void* d_ws, size_t ws_size,
                              hipStream_t stream) {
  const float* sim = (const float*)d_in[0];
  const float* enc = (const float*)d_in[1];
  float* outp = (float*)d_out;
  ushort* Etf = (ushort*)d_ws;  // 32*32*16*64*16 B = 16.8 MB

  enc_to_frag<<<dim3(16, Bn), 256, 0, stream>>>(enc, Etf);
  c2q_fused<<<dim3(2048), 512, 0, stream>>>(sim, Etf, outp);
}